// Round 7
// baseline (2875.210 us; speedup 1.0000x reference)
//
#include <hip/hip_runtime.h>

// 2-layer LSTM (H=256, T=256, B=512, I=2) + linear head.
// R25: 128 blocks x 512 threads, 4 batches/block (MFMA B-cols 0..3 real).
// R24 accounting: per-CU port needs ~16.5k cyc/step but step = 25.4k; the
// gap is per-XCD L2 contention (32 CUs x 1.15MB / 10.6us = 3.5 TB/s = 81%
// of the ~4.3 TB/s per-XCD ceiling). Halving consumers (128 CUs) halves
// per-XCD L2 demand; per-CU MFMA count UNCHANGED (B-matrix had 14 wasted
// cols). LDS: g-bufs grow to [4][1024] (+16KB) -> LDS parks 16->8
// frags/wave (kt6 only; kt7 joins the stream): NSF 144->152 (0 mod 8,
// slot invariant holds), total ~101KB. h padded [4][288] (576B stride:
// 4-batch bfrag stays 2-way banked, not 4-way). U1/U2/y: 2 batches/thread.
// Prediction: dur ~2100-2400us (port floor 7.4us/step + serial);
// Occupancy ~12% (expected: 128 blocks), Mfma 25-30%, VALU 22-28%,
// FETCH ~7-10MB WRITE ~2.5MB (spill detector), absmax ~1.2e-4.
// If dur >= 2700: contention theory dead -> revert 256 blocks, attack
// serial U-chain.
// A-frag (HW-verified R22-R24): lane holds row rt*16+(l&15),
// k=kt*32+(l>>4)*8..+7. B-frag: h[lane&3][kt*32+(l>>4)*8..+7] (cols 4..15
// garbage, discarded). C: col=l&15, row=(l>>4)*4+reg; lanes col<4 store.
// Kept: single stream in consumption order (R24), 8 named rotating bufs,
// rolled gates1/2a loops (R7-R10/R22: big unrolled schedules spill),
// 32 VGPR parks pinned via asm, 2 lgkm-only barriers, c in regs,
// y deferred 1 step, bias/x in U-stages. No cross-block exchange.

typedef float vf2 __attribute__((ext_vector_type(2)));
typedef float v4f __attribute__((ext_vector_type(4)));
typedef _Float16 vh4 __attribute__((ext_vector_type(4)));
typedef _Float16 vh8 __attribute__((ext_vector_type(8)));

#define NT 512
#define TSTEPS 256
#define NSF 152           // streamed frags per wave per step (1KB each)
#define NVPF 32           // VGPR-parked frags per wave (Whh2 ktiles 1..4)
#define NLPF 8            // LDS-parked frags per wave  (Whh2 ktile 6)
#define FRB 1024          // bytes per frag (64 lanes x 16B)
#define VPBASE (1216 * FRB)               // 8 waves x 152 frags
#define LPBASE (1472 * FRB)               // 1216 + 8x32
#define FS 393216         // fp32 table offset (floats) = 1536KB/4

__global__ void prep_kernel(const float* __restrict__ W_ih1,
                            const float* __restrict__ W_hh1,
                            const float* __restrict__ b_ih1,
                            const float* __restrict__ b_hh1,
                            const float* __restrict__ W_ih2,
                            const float* __restrict__ W_hh2,
                            const float* __restrict__ b_ih2,
                            const float* __restrict__ b_hh2,
                            void* __restrict__ ws) {
    const int stride = gridDim.x * blockDim.x;
    const int idx = blockIdx.x * blockDim.x + threadIdx.x;
    _Float16* wh = (_Float16*)ws;
    float* wf = (float*)ws;
    // A-fragment layout (HW-verified): frag = 1KB; halfword index within
    // frag = lane*8 + j; element = M[w*128 + rt*16 + (lane&15)]
    //                               [kt*32 + (lane>>4)*8 + j].
    // Frag index kb = e>>9 (stream region in CONSUMPTION order):
    //   kb<1216: stream, w=kb/152, f=kb%152:
    //     f<64  -> Whh1 rt=f>>3, kt=f&7
    //     f<128 -> Wih2 rt=(f-64)>>3, kt=f&7
    //     else  -> q=f-128: Whh2 rt=q/3, pos=q%3, kt = {0,5,7}[pos]
    //   kb<1472: VGPR park, p2=kb-1216: w=p2>>5, p=p2&31:
    //            Whh2 rt=p>>2, kt=1+(p&3)
    //   else:    LDS park, k3=kb-1472: w=k3>>3, q=k3&7: Whh2 rt=q, kt=6
    for (int e = idx; e < 786432; e += stride) {
        int kb = e >> 9;
        int lane = (e & 511) >> 3, jj = e & 7;
        int w, rt, kt, m;
        if (kb < 1216) {
            w = kb / 152; int f = kb % 152;
            if (f < 64)       { m = 0; rt = f >> 3;        kt = f & 7; }
            else if (f < 128) { m = 1; rt = (f - 64) >> 3; kt = f & 7; }
            else {
                int q = f - 128; m = 2; rt = q / 3; int pos = q % 3;
                kt = (pos == 0) ? 0 : (pos == 1) ? 5 : 7;
            }
        } else if (kb < 1472) {
            int p2 = kb - 1216; w = p2 >> 5; int p = p2 & 31;
            m = 2; rt = p >> 2; kt = 1 + (p & 3);
        } else {
            int k3 = kb - 1472; w = k3 >> 3; int q = k3 & 7;
            m = 2; rt = q; kt = 6;
        }
        int row = w * 128 + rt * 16 + (lane & 15);
        int k   = kt * 32 + ((lane >> 4) << 3) + jj;
        float v = (m == 0) ? W_hh1[row * 256 + k]
                : (m == 1) ? W_ih2[row * 256 + k]
                           : W_hh2[row * 256 + k];
        wh[e] = (_Float16)v;
    }
    for (int j = idx; j < 1024; j += stride) {
        wf[FS + j]        = W_ih1[j * 2 + 0];
        wf[FS + 1024 + j] = W_ih1[j * 2 + 1];
        wf[FS + 2048 + j] = b_ih1[j] + b_hh1[j];
        wf[FS + 3072 + j] = b_ih2[j] + b_hh2[j];
    }
}

__device__ __forceinline__ float sig_(float v) {
    return 1.f / (1.f + __expf(-v));
}
__device__ __forceinline__ float tanh_(float v) {
    return 1.f - 2.f / (__expf(2.f * v) + 1.f);
}
__device__ __forceinline__ v4f mfma16(vh8 a, vh8 b, v4f c) {
    return __builtin_amdgcn_mfma_f32_16x16x32_f16(a, b, c, 0, 0, 0);
}

// lgkm-only barrier: LDS drained, weight-stream vmem stays in flight.
#define BARRIER() __asm__ volatile("s_waitcnt lgkmcnt(0)\ns_barrier" ::: "memory")

__global__ __launch_bounds__(NT, 2) void lstm_kernel(
    const float* __restrict__ x,      // (512, 256, 2)
    const void* __restrict__ ws,
    const float* __restrict__ W_lin,  // (2, 256)
    const float* __restrict__ b_lin,  // (2,)
    float* __restrict__ out)          // (512, 256, 2)
{
    __shared__ float g1buf[4][1024];               // raw Whh1*h1 [batch][row]
    __shared__ float g2buf[4][1024];               // gates2 gemm (partial/final)
    __shared__ __align__(16) _Float16 h1s[4][288]; // h1 [batch][unit], padded
    __shared__ __align__(16) _Float16 h2s[4][288]; // (576B stride: 2-way banks)
    __shared__ __align__(16) char lds_park[NLPF * 8 * FRB]; // 64 KB

    const int tid = threadIdx.x;
    const int lane = tid & 63, w = tid >> 6;       // wave id = rowgroup
    const int u = tid & 255, bu = tid >> 8;        // cell: unit u, batches bu, bu+2
    const int b0 = blockIdx.x * 4;
    const char* wstream = (const char*)ws;
    const float* wf = (const float*)ws;
    const int l16 = lane * 16;

    // U-stage affine constants: rows u, 256+u, 512+u, 768+u
    float wxa[4], wxb[4], b1c[4], b2c[4];
    #pragma unroll
    for (int g = 0; g < 4; ++g) {
        int r = g * 256 + u;
        wxa[g] = wf[FS + r];        wxb[g] = wf[FS + 1024 + r];
        b1c[g] = wf[FS + 2048 + r]; b2c[g] = wf[FS + 3072 + r];
    }

    // y-head: all 8 waves -> (batch ob = w>>1, output oo = w&1)
    const int ob = w >> 1, oo = w & 1;
    const float wl0 = W_lin[oo * 256 + 4 * lane + 0];
    const float wl1 = W_lin[oo * 256 + 4 * lane + 1];
    const float wl2 = W_lin[oo * 256 + 4 * lane + 2];
    const float wl3 = W_lin[oo * 256 + 4 * lane + 3];
    const float blin = b_lin[oo];

    // zero initial h and g1buf (t=0: Whh1*h1(-1) = 0)
    for (int i = tid; i < 4 * 288; i += NT) {
        ((_Float16*)h1s)[i] = (_Float16)0.f;
        ((_Float16*)h2s)[i] = (_Float16)0.f;
    }
    for (int i = tid; i < 4096; i += NT) ((float*)g1buf)[i] = 0.f;

    float c1a = 0.f, c1b = 0.f, c2a = 0.f, c2b = 0.f;

    // stage LDS parks (kt6, q=rt): lds[((q*8+w)<<10)+l16]
    for (int q = 0; q < NLPF; ++q) {
        *(vh8*)&lds_park[(((q << 3) + w) << 10) + l16] =
            *(const vh8*)(wstream + LPBASE + (((w << 3) + q) << 10) + l16);
    }

    // VGPR parks: 32 frags (Whh2 ktiles 1..4 x 8 rowtiles), PINNED.
    vh8 wreg[NVPF];
    #pragma unroll
    for (int p = 0; p < NVPF; ++p) {
        union { vh8 v; float f[4]; } tpk;
        tpk.v = *(const vh8*)(wstream + VPBASE + ((w * NVPF + p) << 10) + l16);
        asm volatile("" : "+v"(tpk.f[0]), "+v"(tpk.f[1]),
                          "+v"(tpk.f[2]), "+v"(tpk.f[3]));
        wreg[p] = tpk.v;
    }

    // single stream: per-wave base, 8 named rotating buffers, uniform sp.
    // Invariant: consumption c (0..151 per step) uses slot c&7 == frag c.
    const char* wbase = wstream + (size_t)w * (NSF * FRB);
    int sp = 0;
    vh8 B0, B1, B2, B3, B4, B5, B6, B7;
    auto LDA = [&](vh8& d) {
        d = *(const vh8*)(wbase + sp + l16);
        sp += FRB; if (sp == NSF * FRB) sp = 0;
    };
    LDA(B0); LDA(B1); LDA(B2); LDA(B3);
    LDA(B4); LDA(B5); LDA(B6); LDA(B7);

    // B-fragment from h LDS: col=lane&15 -> batch lane&3 (cols 4..15
    // garbage, discarded). k = kt*32 + (lane>>4)*8 .. +7.
    auto bfrag = [&](const _Float16 (*hp)[288], int kt) -> vh8 {
        return *(const vh8*)&hp[lane & 3][kt * 32 + ((lane >> 4) << 3)];
    };

    const int bxa = b0 + bu, bxb = b0 + bu + 2;
    vf2 xva = *(const vf2*)(x + (size_t)bxa * 512);   // x(0)
    vf2 xvb = *(const vf2*)(x + (size_t)bxb * 512);

    __syncthreads();   // init barrier (full drain once is fine)

    #pragma unroll 1
    for (int t = 0; t < TSTEPS; ++t) {
        // ---- U1: gates1(t) = g1buf(raw) + b1 + Wih1*x(t) -> h1(t) ----
        {
            float p0 = g1buf[bu][u]       + b1c[0] + wxa[0] * xva.x + wxb[0] * xva.y;
            float p1 = g1buf[bu][256 + u] + b1c[1] + wxa[1] * xva.x + wxb[1] * xva.y;
            float p2 = g1buf[bu][512 + u] + b1c[2] + wxa[2] * xva.x + wxb[2] * xva.y;
            float p3 = g1buf[bu][768 + u] + b1c[3] + wxa[3] * xva.x + wxb[3] * xva.y;
            c1a = sig_(p1) * c1a + sig_(p0) * tanh_(p2);
            h1s[bu][u] = (_Float16)(sig_(p3) * tanh_(c1a));
            float q0 = g1buf[bu + 2][u]       + b1c[0] + wxa[0] * xvb.x + wxb[0] * xvb.y;
            float q1 = g1buf[bu + 2][256 + u] + b1c[1] + wxa[1] * xvb.x + wxb[1] * xvb.y;
            float q2 = g1buf[bu + 2][512 + u] + b1c[2] + wxa[2] * xvb.x + wxb[2] * xvb.y;
            float q3 = g1buf[bu + 2][768 + u] + b1c[3] + wxa[3] * xvb.x + wxb[3] * xvb.y;
            c1b = sig_(q1) * c1b + sig_(q0) * tanh_(q2);
            h1s[bu + 2][u] = (_Float16)(sig_(q3) * tanh_(c1b));
        }
        {   // prefetch x(t+1) (wraps harmlessly)
            const int tn = (t + 1) & (TSTEPS - 1);
            xva = *(const vf2*)(x + (size_t)bxa * 512 + tn * 2);
            xvb = *(const vf2*)(x + (size_t)bxb * 512 + tn * 2);
        }
        BARRIER();   // B1: h1(t) visible; h2(t-1) (from prev U2) visible

        // ---- y(t-1) (deferred; h2(t-1) stable in this epoch) ----
        if (t > 0) {
            vh4 hv = *(const vh4*)&h2s[ob][4 * lane];
            float s = (float)hv.x * wl0 + (float)hv.y * wl1
                    + (float)hv.z * wl2 + (float)hv.w * wl3;
            #pragma unroll
            for (int m = 32; m >= 1; m >>= 1) s += __shfl_xor(s, m, 64);
            if (lane == 0)
                out[(size_t)(b0 + ob) * 512 + (t - 1) * 2 + oo] = s + blin;
        }

        // ---- gates1(t+1) raw = Whh1 * h1(t)  [consumptions 0..63] ----
        #pragma unroll 1
        for (int rt = 0; rt < 8; ++rt) {
            v4f acc = {0.f, 0.f, 0.f, 0.f};
            acc = mfma16(B0, bfrag(h1s, 0), acc); LDA(B0);
            acc = mfma16(B1, bfrag(h1s, 1), acc); LDA(B1);
            acc = mfma16(B2, bfrag(h1s, 2), acc); LDA(B2);
            acc = mfma16(B3, bfrag(h1s, 3), acc); LDA(B3);
            acc = mfma16(B4, bfrag(h1s, 4), acc); LDA(B4);
            acc = mfma16(B5, bfrag(h1s, 5), acc); LDA(B5);
            acc = mfma16(B6, bfrag(h1s, 6), acc); LDA(B6);
            acc = mfma16(B7, bfrag(h1s, 7), acc); LDA(B7);
            if ((lane & 15) < 4)
                *(v4f*)&g1buf[lane & 15][w * 128 + rt * 16 + ((lane >> 4) << 2)] = acc;
        }

        // ---- gates2 pass 2a: partial = Wih2 * h1(t)  [cons. 64..127] ----
        #pragma unroll 1
        for (int rt = 0; rt < 8; ++rt) {
            v4f acc = {0.f, 0.f, 0.f, 0.f};
            acc = mfma16(B0, bfrag(h1s, 0), acc); LDA(B0);
            acc = mfma16(B1, bfrag(h1s, 1), acc); LDA(B1);
            acc = mfma16(B2, bfrag(h1s, 2), acc); LDA(B2);
            acc = mfma16(B3, bfrag(h1s, 3), acc); LDA(B3);
            acc = mfma16(B4, bfrag(h1s, 4), acc); LDA(B4);
            acc = mfma16(B5, bfrag(h1s, 5), acc); LDA(B5);
            acc = mfma16(B6, bfrag(h1s, 6), acc); LDA(B6);
            acc = mfma16(B7, bfrag(h1s, 7), acc); LDA(B7);
            if ((lane & 15) < 4)
                *(v4f*)&g2buf[lane & 15][w * 128 + rt * 16 + ((lane >> 4) << 2)] = acc;
        }

        // ---- gates2 pass 2b: += Whh2 * h2(t-1)  [cons. 128..151 = 8 x
        //      (kt0, kt5, kt7) streamed; kt1..4 VGPR parks (static idx);
        //      kt6 LDS park]. Port stays fed (24KB/wave this phase);
        //      refills wrap into next step's frags 0..7. ----
#define P2B(RT, BA, BB, BC)                                                    \
        {                                                                      \
            v4f acc = {0.f, 0.f, 0.f, 0.f};                                    \
            if ((lane & 15) < 4)                                               \
                acc = *(const v4f*)&g2buf[lane & 15]                           \
                        [w * 128 + RT * 16 + ((lane >> 4) << 2)];              \
            acc = mfma16(BA, bfrag(h2s, 0), acc); LDA(BA);                     \
            acc = mfma16(wreg[RT * 4 + 0], bfrag(h2s, 1), acc);                \
            acc = mfma16(wreg[RT * 4 + 1], bfrag(h2s, 2), acc);                \
            acc = mfma16(wreg[RT * 4 + 2], bfrag(h2s, 3), acc);                \
            acc = mfma16(wreg[RT * 4 + 3], bfrag(h2s, 4), acc);                \
            acc = mfma16(BB, bfrag(h2s, 5), acc); LDA(BB);                     \
            {                                                                  \
                vh8 A6 = *(const vh8*)                                         \
                    &lds_park[(((RT << 3) + w) << 10) + l16];                  \
                acc = mfma16(A6, bfrag(h2s, 6), acc);                          \
            }                                                                  \
            acc = mfma16(BC, bfrag(h2s, 7), acc); LDA(BC);                     \
            if ((lane & 15) < 4)                                               \
                *(v4f*)&g2buf[lane & 15]                                       \
                    [w * 128 + RT * 16 + ((lane >> 4) << 2)] = acc;            \
        }
        // consumption slots: c = 128 + 3*RT + {0,1,2}, slot = c & 7
        P2B(0, B0, B1, B2) P2B(1, B3, B4, B5) P2B(2, B6, B7, B0)
        P2B(3, B1, B2, B3) P2B(4, B4, B5, B6) P2B(5, B7, B0, B1)
        P2B(6, B2, B3, B4) P2B(7, B5, B6, B7)
#undef P2B
        BARRIER();   // B2: g1buf/g2buf visible

        // ---- U2: gates2 + b2 -> h2(t) ----
        {
            float p0 = g2buf[bu][u]       + b2c[0];
            float p1 = g2buf[bu][256 + u] + b2c[1];
            float p2 = g2buf[bu][512 + u] + b2c[2];
            float p3 = g2buf[bu][768 + u] + b2c[3];
            c2a = sig_(p1) * c2a + sig_(p0) * tanh_(p2);
            h2s[bu][u] = (_Float16)(sig_(p3) * tanh_(c2a));
            float q0 = g2buf[bu + 2][u]       + b2c[0];
            float q1 = g2buf[bu + 2][256 + u] + b2c[1];
            float q2 = g2buf[bu + 2][512 + u] + b2c[2];
            float q3 = g2buf[bu + 2][768 + u] + b2c[3];
            c2b = sig_(q1) * c2b + sig_(q0) * tanh_(q2);
            h2s[bu + 2][u] = (_Float16)(sig_(q3) * tanh_(c2b));
        }
        // no barrier: next iteration's B1 publishes h2(t) before it's read
    }

    // ---- tail: y(255) ----
    BARRIER();
    {
        vh4 hv = *(const vh4*)&h2s[ob][4 * lane];
        float s = (float)hv.x * wl0 + (float)hv.y * wl1
                + (float)hv.z * wl2 + (float)hv.w * wl3;
        #pragma unroll
        for (int m = 32; m >= 1; m >>= 1) s += __shfl_xor(s, m, 64);
        if (lane == 0)
            out[(size_t)(b0 + ob) * 512 + 255 * 2 + oo] = s + blin;
    }
}

extern "C" void kernel_launch(void* const* d_in, const int* in_sizes, int n_in,
                              void* d_out, int out_size, void* d_ws, size_t ws_size,
                              hipStream_t stream) {
    const float* x     = (const float*)d_in[0];
    const float* W_ih1 = (const float*)d_in[1];
    const float* W_hh1 = (const float*)d_in[2];
    const float* b_ih1 = (const float*)d_in[3];
    const float* b_hh1 = (const float*)d_in[4];
    const float* W_ih2 = (const float*)d_in[5];
    const float* W_hh2 = (const float*)d_in[6];
    const float* b_ih2 = (const float*)d_in[7];
    const float* b_hh2 = (const float*)d_in[8];
    const float* W_lin = (const float*)d_in[9];
    const float* b_lin = (const float*)d_in[10];
    float* out = (float*)d_out;

    prep_kernel<<<256, 256, 0, stream>>>(W_ih1, W_hh1, b_ih1, b_hh1,
                                         W_ih2, W_hh2, b_ih2, b_hh2, d_ws);
    lstm_kernel<<<128, NT, 0, stream>>>(x, d_ws, W_lin, b_lin, out);
}